// Round 1
// baseline (2394.549 us; speedup 1.0000x reference)
//
#include <hip/hip_runtime.h>
#include <hip/hip_bf16.h>
#include <stdint.h>

// Sizes (fixed by the problem)
#define B_SZ 256
#define H_SZ 1024
#define NG   4096   // 4*H
#define F_SZ 32
#define T_SZ 96

typedef __attribute__((ext_vector_type(8))) short short8;
typedef __attribute__((ext_vector_type(4))) float f32x4;

__device__ __forceinline__ unsigned short f2bf(float x) {
  unsigned int u = __float_as_uint(x);
  u += 0x7fffu + ((u >> 16) & 1u);   // RNE
  return (unsigned short)(u >> 16);
}
__device__ __forceinline__ float sigf(float x) {
  return 1.f / (1.f + __expf(-x));
}
__device__ __forceinline__ float tanh_fast(float x) {
  float e = __expf(-2.f * fabsf(x));
  float t = (1.f - e) / (1.f + e);
  return copysignf(t, x);
}
__device__ __forceinline__ void stage16(const void* g, void* l) {
  __builtin_amdgcn_global_load_lds(
      (const __attribute__((address_space(1))) void*)g,
      (__attribute__((address_space(3))) void*)l, 16, 0, 0);
}

// ---------------------------------------------------------------------------
// Prep 1: build W_effT[n][k] = (W_h + W_dense@W_x)^T and W_hT[n][k], bf16.
// grid 512 = 32 k-tiles x 16 n-tiles, 256 threads. LDS 48KB.
// ---------------------------------------------------------------------------
__global__ __launch_bounds__(256) void k_prep_w(
    const float* __restrict__ Wx, const float* __restrict__ Wh,
    const float* __restrict__ Wd,
    unsigned short* __restrict__ WeffT, unsigned short* __restrict__ WhT)
{
  __shared__ float wx[32 * 256];          // W_x[f][n-tile]
  __shared__ unsigned short res[32 * 256];
  int kt = blockIdx.x & 31, nt = blockIdx.x >> 5;
  int k0 = kt * 32, n0 = nt * 256, tid = threadIdx.x;
  for (int i = 0; i < 32; ++i) {
    int lin = i * 256 + tid;
    wx[lin] = Wx[(size_t)(lin >> 8) * NG + n0 + (lin & 255)];
  }
  for (int pass = 0; pass < 2; ++pass) {
    __syncthreads();
    for (int kr = 0; kr < 32; ++kr) {
      int k = k0 + kr;
      float v = Wh[(size_t)k * NG + n0 + tid];
      if (pass == 0) {
        float acc = 0.f;
#pragma unroll
        for (int f = 0; f < 32; ++f) acc += Wd[k * 32 + f] * wx[f * 256 + tid];
        v += acc;
      }
      res[kr * 256 + tid] = f2bf(v);
    }
    __syncthreads();
    // transpose write: thread owns column n=tid; write 64B row chunk
    unsigned short* dst = (pass == 0 ? WeffT : WhT) + (size_t)(n0 + tid) * H_SZ + k0;
    unsigned int vals[16];
#pragma unroll
    for (int p = 0; p < 16; ++p)
      vals[p] = (unsigned int)res[(2 * p) * 256 + tid] |
                ((unsigned int)res[(2 * p + 1) * 256 + tid] << 16);
#pragma unroll
    for (int qd = 0; qd < 4; ++qd) {
      uint4 v4; v4.x = vals[4*qd]; v4.y = vals[4*qd+1]; v4.z = vals[4*qd+2]; v4.w = vals[4*qd+3];
      ((uint4*)dst)[qd] = v4;
    }
  }
}

// ---------------------------------------------------------------------------
// Prep 2: u0 = b + x0@W_x (fp32, per-row bias for step 0); h0->bf16; c copy;
//         WdT[f][k] bf16; b_eff = b + b_dense@W_x.  grid 1680 x 256.
// ---------------------------------------------------------------------------
__global__ __launch_bounds__(256) void k_prep_small(
    const float* __restrict__ x0, const float* __restrict__ h0,
    const float* __restrict__ c0, const float* __restrict__ Wx,
    const float* __restrict__ bvec, const float* __restrict__ Wd,
    const float* __restrict__ bd,
    float* __restrict__ u0, unsigned short* __restrict__ hb0,
    float* __restrict__ cws, unsigned short* __restrict__ WdT,
    float* __restrict__ beff)
{
  int bid = blockIdx.x, tid = threadIdx.x;
  if (bid < 1024) {                      // u0: 256 x 4096
    int m = bid >> 2;
    int nb = (bid & 3) << 10;
    for (int i = 0; i < 4; ++i) {
      int n = nb + (i << 8) + tid;
      float acc = bvec[n];
#pragma unroll 8
      for (int f = 0; f < 32; ++f) acc += x0[(m << 5) + f] * Wx[(size_t)(f << 12) + n];
      u0[((size_t)m << 12) + n] = acc;
    }
  } else if (bid < 1280) {               // h0 -> bf16
    int i0 = ((bid - 1024) << 10) + tid;
    for (int i = 0; i < 4; ++i) { int idx = i0 + (i << 8); hb0[idx] = f2bf(h0[idx]); }
  } else if (bid < 1536) {               // c copy to ws
    int i0 = ((bid - 1280) << 10) + tid;
    for (int i = 0; i < 4; ++i) { int idx = i0 + (i << 8); cws[idx] = c0[idx]; }
  } else if (bid < 1664) {               // WdT[f][k] = Wd[k][f]
    int idx = ((bid - 1536) << 8) + tid;
    int f = idx >> 10, k = idx & 1023;
    WdT[idx] = f2bf(Wd[k * 32 + f]);
  } else {                               // b_eff
    int n = ((bid - 1664) << 8) + tid;
    float acc = bvec[n];
#pragma unroll 8
    for (int f = 0; f < 32; ++f) acc += bd[f] * Wx[(size_t)(f << 12) + n];
    beff[n] = acc;
  }
}

// ---------------------------------------------------------------------------
// y dot-product helper: y[m][f] = h[m][:] . WdT[f][:] + bd[f]  (bf16 inputs)
// ---------------------------------------------------------------------------
__device__ __forceinline__ void ydot_write(
    const unsigned short* __restrict__ h, const unsigned short* __restrict__ WdT,
    const float* __restrict__ bd, float* __restrict__ out, int m, int f, int t)
{
  const uint4* ha = (const uint4*)(h + (size_t)m * H_SZ);
  const uint4* wa = (const uint4*)(WdT + (size_t)f * H_SZ);
  float acc = 0.f;
#pragma unroll 4
  for (int k8 = 0; k8 < 128; ++k8) {
    uint4 av = ha[k8], wv = wa[k8];
    acc += __uint_as_float(av.x << 16) * __uint_as_float(wv.x << 16);
    acc += __uint_as_float(av.x & 0xffff0000u) * __uint_as_float(wv.x & 0xffff0000u);
    acc += __uint_as_float(av.y << 16) * __uint_as_float(wv.y << 16);
    acc += __uint_as_float(av.y & 0xffff0000u) * __uint_as_float(wv.y & 0xffff0000u);
    acc += __uint_as_float(av.z << 16) * __uint_as_float(wv.z << 16);
    acc += __uint_as_float(av.z & 0xffff0000u) * __uint_as_float(wv.z & 0xffff0000u);
    acc += __uint_as_float(av.w << 16) * __uint_as_float(wv.w << 16);
    acc += __uint_as_float(av.w & 0xffff0000u) * __uint_as_float(wv.w & 0xffff0000u);
  }
  out[((size_t)m * T_SZ + t) * F_SZ + f] = acc + bd[f];
}

// ---------------------------------------------------------------------------
// Step kernel: z = h_prev @ W (+bias), gates, c/h update; 32 extra blocks
// emit y_{j-1}. grid 288 x 256.
// Blocks 0..255: bt (4 batch tiles of 64) x ht (64 hidden tiles of 16).
// Wave = gate. MFMA 16x16x32 bf16. A staged via global_load_lds with
// pre-swizzled source (conflict-free ds_read_b128); B direct 16B loads
// from W_T[n][k].
// ---------------------------------------------------------------------------
__global__ __launch_bounds__(256) void k_step(
    const unsigned short* __restrict__ WT,     // [4096][1024] bf16 bits
    const unsigned short* __restrict__ hprev,  // [256][1024]
    unsigned short* __restrict__ hnext,
    float* __restrict__ cws,
    const float* __restrict__ u0,              // j==0 bias (M x 4096)
    const float* __restrict__ beff,            // j>=1 bias (4096)
    const unsigned short* __restrict__ WdT,    // [32][1024]
    const float* __restrict__ bd,
    float* __restrict__ out, int j)
{
  int b = blockIdx.x;
  int tid = threadIdx.x;

  if (b >= 256) {              // y blocks: y_{j-1} = h^{(j)} @ Wd + bd
    if (j == 0) return;
    int yb = b - 256;
    ydot_write(hprev, WdT, bd, out, yb * 8 + (tid >> 5), tid & 31, j - 1);
    return;
  }

  int lane = tid & 63;
  int g = tid >> 6;                            // wave id = gate
  int ht = ((b & 7) << 3) | ((b >> 3) & 7);    // XCD-local hidden grouping
  int bt = b >> 6;
  int m0 = bt << 6;
  int nh = ht << 4;

  __shared__ unsigned short Abuf[2][4096];     // 2 bufs x 2 k-chunks x 4KB
  __shared__ float zlds[4][64][16];            // gate exchange, 16KB

  // Staging source (pre-swizzled so linear LDS dest => swizzled content).
  // Within a 32-k chunk: pos(m,kg) = m*64B + ((kg ^ ((m>>1)&3))*16B).
  int sm = tid >> 2;
  int skg = (tid & 3) ^ ((tid >> 3) & 3);
  const unsigned short* hsrc = hprev + (size_t)(m0 + sm) * H_SZ + skg * 8;
  int wbase = (tid >> 6) << 9;                 // per-wave dest base (ushorts)

  // A-fragment read offset (ushorts), + mf*512 per m-fragment
  int r = lane & 15;
  int q = (lane >> 4) ^ ((r >> 1) & 3);
  int aoff = r * 32 + q * 8;

  // B fragment pointer: W_T[n][k], n = g*1024 + nh + (lane&15)
  const unsigned short* wp =
      WT + (size_t)((g << 10) + nh + r) * H_SZ + ((lane >> 4) << 3);

  f32x4 acc[4] = {};

  stage16(hsrc,      &Abuf[0][wbase]);
  stage16(hsrc + 32, &Abuf[0][2048 + wbase]);

  for (int kp = 0; kp < 16; ++kp) {
    int cur = kp & 1;
    __syncthreads();                           // staged buf[cur] ready; prev reads done
    if (kp < 15) {
      stage16(hsrc + (kp + 1) * 64,      &Abuf[cur ^ 1][wbase]);
      stage16(hsrc + (kp + 1) * 64 + 32, &Abuf[cur ^ 1][2048 + wbase]);
    }
#pragma unroll
    for (int sub = 0; sub < 2; ++sub) {
      int kk = kp * 2 + sub;
      short8 bfr = *(const short8*)(wp + kk * 32);
      const unsigned short* cb = &Abuf[cur][sub * 2048];
#pragma unroll
      for (int mf = 0; mf < 4; ++mf) {
        short8 af = *(const short8*)(cb + aoff + mf * 512);
        acc[mf] = __builtin_amdgcn_mfma_f32_16x16x32_bf16(af, bfr, acc[mf], 0, 0, 0);
      }
    }
  }

  // Gate exchange: wave g writes its z tile (rows, 16 cols) to LDS.
  // D layout: col = lane&15, row = (lane>>4)*4 + e  [m89-verified]
#pragma unroll
  for (int mf = 0; mf < 4; ++mf)
#pragma unroll
    for (int e = 0; e < 4; ++e)
      zlds[g][mf * 16 + (lane >> 4) * 4 + e][lane & 15] = acc[mf][e];
  __syncthreads();

  // Elementwise cell update: 1024 cells, 4 per thread.
#pragma unroll
  for (int e2 = 0; e2 < 4; ++e2) {
    int idx = e2 * 256 + tid;
    int m = idx >> 4, cc = idx & 15;
    float zi, zf, zg, zo;
    if (j == 0) {
      const float* u = u0 + ((size_t)(m0 + m) << 12) + nh + cc;
      zi = zlds[0][m][cc] + u[0];
      zf = zlds[1][m][cc] + u[1024];
      zg = zlds[2][m][cc] + u[2048];
      zo = zlds[3][m][cc] + u[3072];
    } else {
      zi = zlds[0][m][cc] + beff[nh + cc];
      zf = zlds[1][m][cc] + beff[1024 + nh + cc];
      zg = zlds[2][m][cc] + beff[2048 + nh + cc];
      zo = zlds[3][m][cc] + beff[3072 + nh + cc];
    }
    float iv = sigf(zi), fv = sigf(zf), gv = tanh_fast(zg), ov = sigf(zo);
    size_t cidx = (size_t)(m0 + m) * H_SZ + nh + cc;
    float cn = fv * cws[cidx] + iv * gv;
    cws[cidx] = cn;
    hnext[cidx] = f2bf(ov * tanh_fast(cn));
  }
}

// Final y_95 from h^(96)
__global__ __launch_bounds__(256) void k_ytail(
    const unsigned short* __restrict__ h, const unsigned short* __restrict__ WdT,
    const float* __restrict__ bd, float* __restrict__ out)
{
  int tid = threadIdx.x;
  ydot_write(h, WdT, bd, out, blockIdx.x * 8 + (tid >> 5), tid & 31, 95);
}

// ---------------------------------------------------------------------------
extern "C" void kernel_launch(void* const* d_in, const int* in_sizes, int n_in,
                              void* d_out, int out_size, void* d_ws, size_t ws_size,
                              hipStream_t stream)
{
  const float* x0 = (const float*)d_in[0];   // initial_input (256,1,32)
  const float* h0 = (const float*)d_in[1];   // hidden_h (256,1024)
  const float* c0 = (const float*)d_in[2];   // hidden_c
  // d_in[3] targets: unused (only provides T)
  const float* Wx = (const float*)d_in[4];   // (32,4096)
  const float* Wh = (const float*)d_in[5];   // (1024,4096)
  const float* bv = (const float*)d_in[6];   // (4096)
  const float* Wd = (const float*)d_in[7];   // (1024,32)
  const float* bd = (const float*)d_in[8];   // (32)
  float* out = (float*)d_out;                // (256,96,32) fp32

  char* p = (char*)d_ws;
  unsigned short* WeffT = (unsigned short*)p; p += (size_t)NG * H_SZ * 2;   // 8 MB
  unsigned short* WhT   = (unsigned short*)p; p += (size_t)NG * H_SZ * 2;   // 8 MB
  float* u0             = (float*)p;          p += (size_t)B_SZ * NG * 4;   // 4 MB
  float* cws            = (float*)p;          p += (size_t)B_SZ * H_SZ * 4; // 1 MB
  unsigned short* hb0   = (unsigned short*)p; p += (size_t)B_SZ * H_SZ * 2;
  unsigned short* hb1   = (unsigned short*)p; p += (size_t)B_SZ * H_SZ * 2;
  unsigned short* WdT   = (unsigned short*)p; p += (size_t)F_SZ * H_SZ * 2;
  float* beff           = (float*)p;          p += (size_t)NG * 4;
  (void)ws_size; (void)in_sizes; (void)n_in; (void)out_size;

  k_prep_w<<<dim3(512), dim3(256), 0, stream>>>(Wx, Wh, Wd, WeffT, WhT);
  k_prep_small<<<dim3(1680), dim3(256), 0, stream>>>(x0, h0, c0, Wx, bv, Wd, bd,
                                                     u0, hb0, cws, WdT, beff);
  for (int j = 0; j < T_SZ; ++j) {
    const unsigned short* WT = j ? WeffT : WhT;
    const unsigned short* hp = (j & 1) ? hb1 : hb0;
    unsigned short* hn = (j & 1) ? hb0 : hb1;
    k_step<<<dim3(288), dim3(256), 0, stream>>>(WT, hp, hn, cws, u0, beff,
                                                WdT, bd, out, j);
  }
  k_ytail<<<dim3(32), dim3(256), 0, stream>>>(hb0, WdT, bd, out);
}